// Round 10
// baseline (944.184 us; speedup 1.0000x reference)
//
#include <hip/hip_runtime.h>
#include <stdint.h>

// ============================================================================
// LSTM (B=2048,T=256,D=32,H=256) + FC(256) on gfx950.
// R14 = R10 (best: 513us) + SAME-XCD SHARED-L2 exchange loads (single change).
// Evidence line: R6/R13 (agent atomics) -> atomics serialize at the coherence
// point (WRITE 2x, period 6200cy). R10 (plain sc0sc1 16B ops) -> best, 4810cy
// period, residual ~3300cy = system-scope visibility + blocked retry.
// Unexploited: pair (bt, bt+128) is SAME-XCD (round-robin %8; 128%8==0) ->
// producer and consumer SHARE an L2. R10's system-scope ops bypass it.
//  - store (unchanged): global_store_dwordx4 sc0 sc1 -- writes THROUGH the
//    shared L2 (updating it) and pushes to memory (proven visible, R10).
//  - loads (the change): sc0-only -> bypass L1, served by the SHARED L2:
//    same-XCD visibility ~300-500cy < post-to-check slack -> first check hits.
//  - hang-proofing (R12 lesson): if pairing is ever cross-XCD or the store
//    doesn't update L2, an sc0 retry could re-hit a stale L2 line forever.
//    Retry ladder: tries 0..15 sc0 (fast path), tries >=16 sc0 sc1 (system
//    scope, R10-proven visible -> bounded worst case, never deadlock).
// Everything else identical to R10: 256 blocks = 128 batch-tiles x 2
// col-groups, 512 thr (8 waves), 1 block/CU; wave w owns hidden units
// cg*128+w*16..+16, all 4 gates; 36 weight frags pinned resident; GEMM split
// local (own h-half + x) / remote (sibling half); slab dword = h|tag<<16,
// every dword self-validates (torn/stale -> retry, never accepted); parity
// double-buffer + recurrence dep = WAR-safe; lgkm-only barriers in-loop.
// MFMA layouts (learn_hip verified): A[m=lane&15][k=(lane>>4)*8+j],
// B^T same, C/D: col=lane&15, row=(lane>>4)*4+reg.
// ============================================================================

typedef __attribute__((ext_vector_type(8))) short short8;
typedef __attribute__((ext_vector_type(4))) float f32x4;
typedef __attribute__((ext_vector_type(4))) uint32_t u32x4;
typedef unsigned long long ull;

#define LDSTRIDE 296  // 288 K-cols + 8 pad shorts
#define NBT 128       // batch tiles

// lgkm-only barrier: LDS visibility across waves WITHOUT draining VMEM.
#define BARRIER_LGKM() \
  asm volatile("s_waitcnt lgkmcnt(0)\n\ts_barrier" ::: "memory")

__device__ __forceinline__ short f2bf(float f) {
  uint32_t u = __builtin_bit_cast(uint32_t, f);
  u = (u + 0x7FFFu + ((u >> 16) & 1u)) >> 16;  // RNE
  return (short)(uint16_t)u;
}

#define LOG2E 1.4426950408889634f
__device__ __forceinline__ float sigmoidf_(float x) {
  return __builtin_amdgcn_rcpf(1.0f + __builtin_amdgcn_exp2f(-LOG2E * x));
}
__device__ __forceinline__ float tanhf_(float x) {
  float t = __builtin_amdgcn_exp2f((2.0f * LOG2E) * x);
  return 1.0f - 2.0f * __builtin_amdgcn_rcpf(t + 1.0f);
}

// 16B load, bypass L1, served by the (shared, same-XCD) L2. Wait inside.
__device__ __forceinline__ u32x4 load16_l2(const uint32_t* p) {
  u32x4 r;
  asm volatile("global_load_dwordx4 %0, %1, off sc0\n\ts_waitcnt vmcnt(0)"
               : "=v"(r)
               : "v"(p)
               : "memory");
  return r;
}
// 16B system-scope load (bypass L1+L2; R10-proven to observe the stores).
__device__ __forceinline__ u32x4 load16_sys(const uint32_t* p) {
  u32x4 r;
  asm volatile("global_load_dwordx4 %0, %1, off sc0 sc1\n\ts_waitcnt vmcnt(0)"
               : "=v"(r)
               : "v"(p)
               : "memory");
  return r;
}
// 16B store: write-through shared L2 + push to memory (non-atomic; dwords
// self-validate via embedded tags). Unchanged from R10.
__device__ __forceinline__ void store16_sc(uint32_t* p, u32x4 v) {
  asm volatile("global_store_dwordx4 %0, %1, off sc0 sc1" ::"v"(p), "v"(v)
               : "memory");
}

// zero the 4MB xchg buffer (tags must start != 1..256; also clears prev-run
// leftovers whose final tag is 256)
__global__ void zero_xchg(ull* __restrict__ x) {
  size_t i = ((size_t)blockIdx.x * 256 + threadIdx.x) * 4;
  x[i] = 0; x[i + 1] = 0; x[i + 2] = 0; x[i + 3] = 0;
}

// ---------------------------------------------------------------------------
// Pack W_hh[1024x256] (k 0..255) + W_ih[1024x32] (k 256..287) into bf16 frags.
// frag = ((kt*2 + cg)*8 + hu)*4 + g ; element (lane,j):
//   n = g*256 + cg*128 + hu*16 + (lane&15), k = kt*32 + (lane>>4)*8 + j
// ---------------------------------------------------------------------------
__global__ void pack_w(const float* __restrict__ Whh, const float* __restrict__ Wih,
                       short* __restrict__ wpack) {
  int tid = blockIdx.x * 256 + threadIdx.x;  // 576 frags * 64 lanes
  if (tid >= 576 * 64) return;
  int lane = tid & 63;
  int frag = tid >> 6;
  int g = frag & 3, hu = (frag >> 2) & 7, cg = (frag >> 5) & 1, kt = frag >> 6;
  int n = g * 256 + cg * 128 + hu * 16 + (lane & 15);
  int k0 = kt * 32 + (lane >> 4) * 8;
  short8 v;
#pragma unroll
  for (int j = 0; j < 8; ++j) {
    int k = k0 + j;
    float f = (k < 256) ? Whh[n * 256 + k] : Wih[n * 32 + (k - 256)];
    v[j] = f2bf(f);
  }
  *(short8*)(wpack + (size_t)frag * 512 + lane * 8) = v;
}

// W_fc[256x256] -> frags (kt 0..7, ct 0..15): n = ct*16+(lane&15).
__global__ void pack_wfc(const float* __restrict__ Wfc, short* __restrict__ wfc) {
  int tid = blockIdx.x * 256 + threadIdx.x;  // 128 frags * 64 lanes
  if (tid >= 128 * 64) return;
  int lane = tid & 63;
  int frag = tid >> 6;
  int ct = frag & 15, kt = frag >> 4;
  int n = ct * 16 + (lane & 15);
  int k0 = kt * 32 + (lane >> 4) * 8;
  short8 v;
#pragma unroll
  for (int j = 0; j < 8; ++j) v[j] = f2bf(Wfc[n * 256 + k0 + j]);
  *(short8*)(wfc + (size_t)frag * 512 + lane * 8) = v;
}

// slab dword index: [parity][bt][cg][tid] x 4 dwords (16B per thread)
#define SLABD(p, c) (((((size_t)(p)) * NBT + bt) * 2 + (c)) * 512 + tid) * 4

// ---------------------------------------------------------------------------
// Main kernel: grid 256; bt = blockIdx&127, cg = blockIdx>>7 (same-XCD pair).
// ---------------------------------------------------------------------------
__global__ __launch_bounds__(512, 2) void lstm_main(
    const float* __restrict__ obs, const short8* __restrict__ wpack,
    const short8* __restrict__ wfc, const float* __restrict__ b_ih,
    const float* __restrict__ b_hh, const float* __restrict__ b_fc,
    uint32_t* __restrict__ xchg, float* __restrict__ out) {
  __shared__ __align__(16) short A[2][16 * LDSTRIDE];  // parity double-buffer
  const int tid = threadIdx.x;
  const int w = tid >> 6, lane = tid & 63;
  const int l15 = lane & 15, quad = lane >> 4;
  const int bt = blockIdx.x & 127, cg = blockIdx.x >> 7;
  const int row0 = bt * 16;
  const int xr = tid >> 5, xd = tid & 31;  // x staging: row, d
  const int kro = (cg ^ 1) * 4;            // remote ktile base
  const int klo = cg * 4;                  // local ktile base

  // zero both A buffers (h_0 = 0)
  {
    short* Az = &A[0][0];
    for (int i = tid; i < 2 * 16 * LDSTRIDE; i += 512) Az[i] = 0;
  }

  // persistent weight registers: 36 frags (live in the unified RF)
  short8 wfr[9][4];
#pragma unroll
  for (int kt = 0; kt < 9; ++kt)
#pragma unroll
    for (int g = 0; g < 4; ++g)
      wfr[kt][g] = wpack[(size_t)(((kt * 2 + cg) * 8 + w) * 4 + g) * 64 + lane];
#pragma unroll
  for (int kt = 0; kt < 9; ++kt)
#pragma unroll
    for (int g = 0; g < 4; ++g)
      asm volatile("" : "+v"(wfr[kt][g]));  // R9 pin (anti-remat insurance)

  // fused bias per gate for this lane's hidden unit (col = cg*128+w*16+l15)
  float bias[4];
#pragma unroll
  for (int g = 0; g < 4; ++g) {
    int idx = g * 256 + cg * 128 + w * 16 + l15;
    bias[g] = b_ih[idx] + b_hh[idx];
  }

  float c4[4];
#pragma unroll
  for (int i = 0; i < 4; ++i) c4[i] = 0.f;

  __syncthreads();  // zeroing done (cold path: full barrier fine)
  A[0][xr * LDSTRIDE + 256 + xd] =
      f2bf(obs[((size_t)(row0 + xr) * 256 + 0) * 32 + xd]);
  __syncthreads();  // x_0 staged

// 4 MFMAs (all gates) for one compile-time ktile (wfr index must be constant)
#define MFK(KT)                                                                \
  {                                                                            \
    const short8 a_ =                                                          \
        *(const short8*)&Acur[l15 * LDSTRIDE + (KT)*32 + quad * 8];            \
    acc[0] = __builtin_amdgcn_mfma_f32_16x16x32_bf16(a_, wfr[KT][0], acc[0],   \
                                                     0, 0, 0);                 \
    acc[1] = __builtin_amdgcn_mfma_f32_16x16x32_bf16(a_, wfr[KT][1], acc[1],   \
                                                     0, 0, 0);                 \
    acc[2] = __builtin_amdgcn_mfma_f32_16x16x32_bf16(a_, wfr[KT][2], acc[2],   \
                                                     0, 0, 0);                 \
    acc[3] = __builtin_amdgcn_mfma_f32_16x16x32_bf16(a_, wfr[KT][3], acc[3],   \
                                                     0, 0, 0);                 \
  }

  for (int t = 0; t < 256; ++t) {
    const int p = t & 1;
    short* __restrict__ Acur = &A[p][0];
    short* __restrict__ Anx = &A[p ^ 1][0];
    const int tn = (t < 255) ? (t + 1) : 255;

    // early-issue speculative sibling slab load (16B, sc0: shared-L2 path;
    // stale data harmless -- every dword self-validates). Latency overlaps
    // the local GEMM. "memory" clobber pins the obs load AFTER this issue so
    // the vmcnt(1) below leaves exactly the obs prefetch in flight.
    const uint32_t* sa = xchg + SLABD(p, cg ^ 1);
    u32x4 sv = (u32x4){0, 0, 0, 0};
    if (t > 0)
      asm volatile("global_load_dwordx4 %0, %1, off sc0"
                   : "=v"(sv)
                   : "v"(sa)
                   : "memory");

    // obs prefetch x_{t+1} (consumed at phase 6; stays in flight)
    const float xv = obs[((size_t)(row0 + xr) * 256 + tn) * 32 + xd];

    // phase 1: LOCAL GEMM (own h-half + x) -- needs nothing from sibling
    f32x4 acc[4];
#pragma unroll
    for (int g = 0; g < 4; ++g)
      acc[g] = (f32x4){bias[g], bias[g], bias[g], bias[g]};
    if (cg == 0) { MFK(0) MFK(1) MFK(2) MFK(3) }
    else         { MFK(4) MFK(5) MFK(6) MFK(7) }
    MFK(8)  // x ktile

    // phase 2: validate tags / ladder-poll, scatter into Acur sib-half
    if (t > 0) {
      // wait for the speculative load only (obs prefetch stays outstanding);
      // "+v"(sv) ties the wait to the data so uses cannot be hoisted (rule 18)
      asm volatile("s_waitcnt vmcnt(1)" : "+v"(sv)::"memory");
      __builtin_amdgcn_sched_barrier(0);
      const uint32_t want = (uint32_t)t << 16;
      int tries = 0;
      for (;;) {
        const uint32_t bad = ((sv[0] ^ want) | (sv[1] ^ want) | (sv[2] ^ want) |
                              (sv[3] ^ want)) & 0xFFFF0000u;
        if (!bad) break;
        __builtin_amdgcn_s_sleep(2);  // ~128cy backoff
        // ladder: fast shared-L2 retries, then PROVEN system-scope fallback
        // (guards the cross-XCD / stale-line pathology -- bounded, no hang)
        sv = (++tries < 16) ? load16_l2(sa) : load16_sys(sa);
      }
      const int scol = kro * 32 + w * 16 + l15;
      Acur[(quad * 4 + 0) * LDSTRIDE + scol] = (short)(uint16_t)sv[0];
      Acur[(quad * 4 + 1) * LDSTRIDE + scol] = (short)(uint16_t)sv[1];
      Acur[(quad * 4 + 2) * LDSTRIDE + scol] = (short)(uint16_t)sv[2];
      Acur[(quad * 4 + 3) * LDSTRIDE + scol] = (short)(uint16_t)sv[3];
    }
    // phase 3: sib-half visible to all waves (LDS-only visibility)
    BARRIER_LGKM();

    // phase 4: REMOTE GEMM (sibling h-half)
    if (cg == 0) { MFK(4) MFK(5) MFK(6) MFK(7) }
    else         { MFK(0) MFK(1) MFK(2) MFK(3) }

    // phase 5: gates
    short hb[4];
#pragma unroll
    for (int reg = 0; reg < 4; ++reg) {
      float iv = sigmoidf_(acc[0][reg]);
      float fv = sigmoidf_(acc[1][reg]);
      float gv = tanhf_(acc[2][reg]);
      float ov = sigmoidf_(acc[3][reg]);
      float cc = fv * c4[reg] + iv * gv;
      c4[reg] = cc;
      hb[reg] = f2bf(ov * tanhf_(cc));
    }

    // phase 6: ONE tagged 16B store (write-through shared L2 + memory), then
    // LDS writes for the local halves.
    {
      const uint32_t tg1 = (uint32_t)(t + 1) << 16;
      uint32_t* ds = xchg + SLABD((t + 1) & 1, cg);
      u32x4 pv = (u32x4){tg1 | (uint16_t)hb[0], tg1 | (uint16_t)hb[1],
                         tg1 | (uint16_t)hb[2], tg1 | (uint16_t)hb[3]};
      store16_sc(ds, pv);
    }
    {
      const int ocol = klo * 32 + w * 16 + l15;
#pragma unroll
      for (int reg = 0; reg < 4; ++reg)
        Anx[(quad * 4 + reg) * LDSTRIDE + ocol] = hb[reg];
      Anx[xr * LDSTRIDE + 256 + xd] = f2bf(xv);
    }
    // phase 7: own-half h_{t+1} + x_{t+1} visible (LDS-only; the slab store's
    // ack must NOT gate the next step)
    BARRIER_LGKM();
  }
#undef MFK

  // ---- final exchange: complete h_256 (parity 0, tag 256) for the FC ----
  {
    const uint32_t* sa = xchg + SLABD(0, cg ^ 1);
    const uint32_t want = 256u << 16;
    int tries = 0;
    u32x4 sv = load16_l2(sa);
    for (;;) {
      const uint32_t bad = ((sv[0] ^ want) | (sv[1] ^ want) | (sv[2] ^ want) |
                            (sv[3] ^ want)) & 0xFFFF0000u;
      if (!bad) break;
      __builtin_amdgcn_s_sleep(2);
      sv = (++tries < 16) ? load16_l2(sa) : load16_sys(sa);
    }
    const int scol = kro * 32 + w * 16 + l15;
    A[0][(quad * 4 + 0) * LDSTRIDE + scol] = (short)(uint16_t)sv[0];
    A[0][(quad * 4 + 1) * LDSTRIDE + scol] = (short)(uint16_t)sv[1];
    A[0][(quad * 4 + 2) * LDSTRIDE + scol] = (short)(uint16_t)sv[2];
    A[0][(quad * 4 + 3) * LDSTRIDE + scol] = (short)(uint16_t)sv[3];
  }
  __syncthreads();  // cold path: full barrier fine

  // FC epilogue: wave w -> out rows bt*16..+16, cols (cg*8+w)*16..+16
  {
    const int ct = cg * 8 + w;
    const int col = ct * 16 + l15;
    const float bv = b_fc[col];
    f32x4 ao = (f32x4){0.f, 0.f, 0.f, 0.f};
#pragma unroll
    for (int kt = 0; kt < 8; ++kt) {
      const short8 a = *(const short8*)&A[0][l15 * LDSTRIDE + kt * 32 + quad * 8];
      const short8 b = wfc[(size_t)(kt * 16 + ct) * 64 + lane];
      ao = __builtin_amdgcn_mfma_f32_16x16x32_bf16(a, b, ao, 0, 0, 0);
    }
#pragma unroll
    for (int reg = 0; reg < 4; ++reg) {
      const int row = row0 + quad * 4 + reg;
      out[(size_t)row * 256 + col] = ao[reg] + bv;
    }
  }
}

extern "C" void kernel_launch(void* const* d_in, const int* in_sizes, int n_in,
                              void* d_out, int out_size, void* d_ws, size_t ws_size,
                              hipStream_t stream) {
  const float* obs  = (const float*)d_in[0];   // [2048,256,32]
  const float* W_ih = (const float*)d_in[1];   // [1024,32]
  const float* W_hh = (const float*)d_in[2];   // [1024,256]
  const float* b_ih = (const float*)d_in[3];   // [1024]
  const float* b_hh = (const float*)d_in[4];   // [1024]
  const float* W_fc = (const float*)d_in[5];   // [256,256]
  const float* b_fc = (const float*)d_in[6];   // [256]
  float* out = (float*)d_out;                  // [2048,256]

  // ws layout
  short*    wpack = (short*)d_ws;                      // 576*512 shorts = 576 KB
  short*    wfcp  = wpack + 576 * 512;                 // 128*512 shorts = 128 KB
  uint32_t* xchg  = (uint32_t*)((char*)d_ws + (576 + 128) * 1024);  // 4 MB slabs

  hipLaunchKernelGGL(zero_xchg, dim3(512), dim3(256), 0, stream, (ull*)xchg);
  hipLaunchKernelGGL(pack_w, dim3(144), dim3(256), 0, stream, W_hh, W_ih, wpack);
  hipLaunchKernelGGL(pack_wfc, dim3(32), dim3(256), 0, stream, W_fc, wfcp);
  hipLaunchKernelGGL(lstm_main, dim3(256), dim3(512), 0, stream, obs,
                     (const short8*)wpack, (const short8*)wfcp,
                     b_ih, b_hh, b_fc, xchg, out);
}

// Round 11
// 563.325 us; speedup vs baseline: 1.6761x; 1.6761x over previous
//
#include <hip/hip_runtime.h>
#include <stdint.h>

// ============================================================================
// LSTM (B=2048,T=256,D=32,H=256) + FC(256) on gfx950.
// R15 = R10 + SHARED-L2 rendezvous: plain stores (write INTO the writeback
// L2) + sc0 loads (read that same L2), with a system-scope MIRROR fallback.
// Hardware rule established R12/R14: a bypassing store leaves stale copies
// at the levels it bypasses (R14: sc0-allocated L2 line pinned stale under
// sc0sc1 stores -> 16-retry storms). Therefore the fast path must pair a
// store that UPDATES a level with a load that READS that level. For the
// same-XCD pair (bt, bt+128: 256-blk round robin %8, 128%8==0) that level is
// the shared L2: plain store hits/updates (writeback, write-allocate-or-
// update-on-hit; the consumer's own spec load allocates the line, after
// which producer stores hit it) -- delta drops from ~2400cy (MALL, R10's
// P=2*delta=4810) to ~200-400cy -> P becomes compute-bound.
// Safety: producer DUAL-POSTS every step: plain 16B store to the L2 slab +
// sc0sc1 16B store to a disjoint MIRROR (R10-proven system-visible).
// Consumer ladder: sc0 slab x4 -> mirror sc0sc1, STICKY (first failure
// switches that thread to mirror-first for all remaining steps). Worst case
// = R10 behavior; no stale-line spin possible (mirror never cached).
// Everything else identical to R10 (best verified: 513us): 256 blocks =
// 128 batch-tiles x 2 col-groups, 512 thr (8 waves), 1 block/CU; wave w owns
// hidden units cg*128+w*16..+16, all 4 gates; 36 weight frags pinned
// resident; GEMM split local (own h-half + x, 20 MFMA) / remote (sibling
// half, 16 MFMA); slab dword = h|tag<<16, every dword self-validates
// (torn/stale -> retry, never accepted); parity double-buffer + recurrence
// dep = WAR-safe (check of tag t globally completes before post of t+1 is
// issued -- data dependence); lgkm-only barriers in the hot loop.
// MFMA layouts (learn_hip verified): A[m=lane&15][k=(lane>>4)*8+j],
// B^T same, C/D: col=lane&15, row=(lane>>4)*4+reg.
// ============================================================================

typedef __attribute__((ext_vector_type(8))) short short8;
typedef __attribute__((ext_vector_type(4))) float f32x4;
typedef __attribute__((ext_vector_type(4))) uint32_t u32x4;
typedef unsigned long long ull;

#define LDSTRIDE 296  // 288 K-cols + 8 pad shorts
#define NBT 128       // batch tiles
// mirror offset in dwords: one full slab region = 2par*128bt*2cg*512thr*4dw
#define MIRROR_OFF (2u * NBT * 2u * 512u * 4u)  // 1048576 dwords = 4 MB

// lgkm-only barrier: LDS visibility across waves WITHOUT draining VMEM.
#define BARRIER_LGKM() \
  asm volatile("s_waitcnt lgkmcnt(0)\n\ts_barrier" ::: "memory")

__device__ __forceinline__ short f2bf(float f) {
  uint32_t u = __builtin_bit_cast(uint32_t, f);
  u = (u + 0x7FFFu + ((u >> 16) & 1u)) >> 16;  // RNE
  return (short)(uint16_t)u;
}

#define LOG2E 1.4426950408889634f
__device__ __forceinline__ float sigmoidf_(float x) {
  return __builtin_amdgcn_rcpf(1.0f + __builtin_amdgcn_exp2f(-LOG2E * x));
}
__device__ __forceinline__ float tanhf_(float x) {
  float t = __builtin_amdgcn_exp2f((2.0f * LOG2E) * x);
  return 1.0f - 2.0f * __builtin_amdgcn_rcpf(t + 1.0f);
}

// 16B load, bypass L1, served by the (shared, same-XCD) L2. Wait inside.
__device__ __forceinline__ u32x4 load16_l2(const uint32_t* p) {
  u32x4 r;
  asm volatile("global_load_dwordx4 %0, %1, off sc0\n\ts_waitcnt vmcnt(0)"
               : "=v"(r)
               : "v"(p)
               : "memory");
  return r;
}
// 16B system-scope load (bypass L1+L2; R10-proven to observe sc0sc1 stores).
__device__ __forceinline__ u32x4 load16_sys(const uint32_t* p) {
  u32x4 r;
  asm volatile("global_load_dwordx4 %0, %1, off sc0 sc1\n\ts_waitcnt vmcnt(0)"
               : "=v"(r)
               : "v"(p)
               : "memory");
  return r;
}

// zero the 8MB xchg region (slab + mirror; tags must start != 1..256)
__global__ void zero_xchg(ull* __restrict__ x) {
  size_t i = ((size_t)blockIdx.x * 256 + threadIdx.x) * 4;
  x[i] = 0; x[i + 1] = 0; x[i + 2] = 0; x[i + 3] = 0;
}

// ---------------------------------------------------------------------------
// Pack W_hh[1024x256] (k 0..255) + W_ih[1024x32] (k 256..287) into bf16 frags.
// frag = ((kt*2 + cg)*8 + hu)*4 + g ; element (lane,j):
//   n = g*256 + cg*128 + hu*16 + (lane&15), k = kt*32 + (lane>>4)*8 + j
// ---------------------------------------------------------------------------
__global__ void pack_w(const float* __restrict__ Whh, const float* __restrict__ Wih,
                       short* __restrict__ wpack) {
  int tid = blockIdx.x * 256 + threadIdx.x;  // 576 frags * 64 lanes
  if (tid >= 576 * 64) return;
  int lane = tid & 63;
  int frag = tid >> 6;
  int g = frag & 3, hu = (frag >> 2) & 7, cg = (frag >> 5) & 1, kt = frag >> 6;
  int n = g * 256 + cg * 128 + hu * 16 + (lane & 15);
  int k0 = kt * 32 + (lane >> 4) * 8;
  short8 v;
#pragma unroll
  for (int j = 0; j < 8; ++j) {
    int k = k0 + j;
    float f = (k < 256) ? Whh[n * 256 + k] : Wih[n * 32 + (k - 256)];
    v[j] = f2bf(f);
  }
  *(short8*)(wpack + (size_t)frag * 512 + lane * 8) = v;
}

// W_fc[256x256] -> frags (kt 0..7, ct 0..15): n = ct*16+(lane&15).
__global__ void pack_wfc(const float* __restrict__ Wfc, short* __restrict__ wfc) {
  int tid = blockIdx.x * 256 + threadIdx.x;  // 128 frags * 64 lanes
  if (tid >= 128 * 64) return;
  int lane = tid & 63;
  int frag = tid >> 6;
  int ct = frag & 15, kt = frag >> 4;
  int n = ct * 16 + (lane & 15);
  int k0 = kt * 32 + (lane >> 4) * 8;
  short8 v;
#pragma unroll
  for (int j = 0; j < 8; ++j) v[j] = f2bf(Wfc[n * 256 + k0 + j]);
  *(short8*)(wfc + (size_t)frag * 512 + lane * 8) = v;
}

// slab dword index: [parity][bt][cg][tid] x 4 dwords (16B per thread)
#define SLABD(p, c) (((((size_t)(p)) * NBT + bt) * 2 + (c)) * 512 + tid) * 4

// ---------------------------------------------------------------------------
// Main kernel: grid 256; bt = blockIdx&127, cg = blockIdx>>7 (same-XCD pair).
// ---------------------------------------------------------------------------
__global__ __launch_bounds__(512, 2) void lstm_main(
    const float* __restrict__ obs, const short8* __restrict__ wpack,
    const short8* __restrict__ wfc, const float* __restrict__ b_ih,
    const float* __restrict__ b_hh, const float* __restrict__ b_fc,
    uint32_t* __restrict__ xchg, float* __restrict__ out) {
  __shared__ __align__(16) short A[2][16 * LDSTRIDE];  // parity double-buffer
  const int tid = threadIdx.x;
  const int w = tid >> 6, lane = tid & 63;
  const int l15 = lane & 15, quad = lane >> 4;
  const int bt = blockIdx.x & 127, cg = blockIdx.x >> 7;
  const int row0 = bt * 16;
  const int xr = tid >> 5, xd = tid & 31;  // x staging: row, d
  const int kro = (cg ^ 1) * 4;            // remote ktile base
  const int klo = cg * 4;                  // local ktile base

  // zero both A buffers (h_0 = 0)
  {
    short* Az = &A[0][0];
    for (int i = tid; i < 2 * 16 * LDSTRIDE; i += 512) Az[i] = 0;
  }

  // persistent weight registers: 36 frags (live in the unified RF)
  short8 wfr[9][4];
#pragma unroll
  for (int kt = 0; kt < 9; ++kt)
#pragma unroll
    for (int g = 0; g < 4; ++g)
      wfr[kt][g] = wpack[(size_t)(((kt * 2 + cg) * 8 + w) * 4 + g) * 64 + lane];
#pragma unroll
  for (int kt = 0; kt < 9; ++kt)
#pragma unroll
    for (int g = 0; g < 4; ++g)
      asm volatile("" : "+v"(wfr[kt][g]));  // R9 pin (anti-remat insurance)

  // fused bias per gate for this lane's hidden unit (col = cg*128+w*16+l15)
  float bias[4];
#pragma unroll
  for (int g = 0; g < 4; ++g) {
    int idx = g * 256 + cg * 128 + w * 16 + l15;
    bias[g] = b_ih[idx] + b_hh[idx];
  }

  float c4[4];
#pragma unroll
  for (int i = 0; i < 4; ++i) c4[i] = 0.f;

  int fast = 1;  // sticky: 1 = shared-L2 fast path; drops to 0 on failure

  __syncthreads();  // zeroing done (cold path: full barrier fine)
  A[0][xr * LDSTRIDE + 256 + xd] =
      f2bf(obs[((size_t)(row0 + xr) * 256 + 0) * 32 + xd]);
  __syncthreads();  // x_0 staged

// 4 MFMAs (all gates) for one compile-time ktile (wfr index must be constant)
#define MFK(KT)                                                                \
  {                                                                            \
    const short8 a_ =                                                          \
        *(const short8*)&Acur[l15 * LDSTRIDE + (KT)*32 + quad * 8];            \
    acc[0] = __builtin_amdgcn_mfma_f32_16x16x32_bf16(a_, wfr[KT][0], acc[0],   \
                                                     0, 0, 0);                 \
    acc[1] = __builtin_amdgcn_mfma_f32_16x16x32_bf16(a_, wfr[KT][1], acc[1],   \
                                                     0, 0, 0);                 \
    acc[2] = __builtin_amdgcn_mfma_f32_16x16x32_bf16(a_, wfr[KT][2], acc[2],   \
                                                     0, 0, 0);                 \
    acc[3] = __builtin_amdgcn_mfma_f32_16x16x32_bf16(a_, wfr[KT][3], acc[3],   \
                                                     0, 0, 0);                 \
  }

  for (int t = 0; t < 256; ++t) {
    const int p = t & 1;
    short* __restrict__ Acur = &A[p][0];
    short* __restrict__ Anx = &A[p ^ 1][0];
    const int tn = (t < 255) ? (t + 1) : 255;

    // early-issue speculative sibling slab load. Fast path: sc0 -> shared L2
    // (the plain store below UPDATES that L2 -> no stale-line pinning, the
    // R14 pathology is structurally impossible). Fallback: mirror, sc0sc1.
    // Stale/torn data harmless -- every dword self-validates.
    const uint32_t* sa = xchg + SLABD(p, cg ^ 1);          // L2 slab
    const uint32_t* sam = sa + MIRROR_OFF;                 // system mirror
    u32x4 sv = (u32x4){0, 0, 0, 0};
    if (t > 0) {
      if (fast)
        asm volatile("global_load_dwordx4 %0, %1, off sc0"
                     : "=v"(sv)
                     : "v"(sa)
                     : "memory");
      else
        asm volatile("global_load_dwordx4 %0, %1, off sc0 sc1"
                     : "=v"(sv)
                     : "v"(sam)
                     : "memory");
    }

    // obs prefetch x_{t+1} (consumed at phase 6; stays in flight)
    const float xv = obs[((size_t)(row0 + xr) * 256 + tn) * 32 + xd];

    // phase 1: LOCAL GEMM (own h-half + x) -- needs nothing from sibling
    f32x4 acc[4];
#pragma unroll
    for (int g = 0; g < 4; ++g)
      acc[g] = (f32x4){bias[g], bias[g], bias[g], bias[g]};
    if (cg == 0) { MFK(0) MFK(1) MFK(2) MFK(3) }
    else         { MFK(4) MFK(5) MFK(6) MFK(7) }
    MFK(8)  // x ktile

    // phase 2: validate tags / sticky-ladder poll, scatter into Acur sib-half
    if (t > 0) {
      // wait for the speculative load only (obs prefetch stays outstanding);
      // "+v"(sv) ties the wait to the data so uses cannot be hoisted (rule 18)
      asm volatile("s_waitcnt vmcnt(1)" : "+v"(sv)::"memory");
      __builtin_amdgcn_sched_barrier(0);
      const uint32_t want = (uint32_t)t << 16;
      int tries = 0;
      for (;;) {
        const uint32_t bad = ((sv[0] ^ want) | (sv[1] ^ want) | (sv[2] ^ want) |
                              (sv[3] ^ want)) & 0xFFFF0000u;
        if (!bad) break;
        if (fast) {
          __builtin_amdgcn_s_sleep(1);  // short backoff, L2 is cheap
          if (++tries >= 4) {
            fast = 0;  // sticky: placement/visibility bad -> mirror-first
            sv = load16_sys(sam);
          } else {
            sv = load16_l2(sa);
          }
        } else {
          __builtin_amdgcn_s_sleep(2);
          sv = load16_sys(sam);
        }
      }
      const int scol = kro * 32 + w * 16 + l15;
      Acur[(quad * 4 + 0) * LDSTRIDE + scol] = (short)(uint16_t)sv[0];
      Acur[(quad * 4 + 1) * LDSTRIDE + scol] = (short)(uint16_t)sv[1];
      Acur[(quad * 4 + 2) * LDSTRIDE + scol] = (short)(uint16_t)sv[2];
      Acur[(quad * 4 + 3) * LDSTRIDE + scol] = (short)(uint16_t)sv[3];
    }
    // phase 3: sib-half visible to all waves (LDS-only visibility)
    BARRIER_LGKM();

    // phase 4: REMOTE GEMM (sibling h-half)
    if (cg == 0) { MFK(4) MFK(5) MFK(6) MFK(7) }
    else         { MFK(0) MFK(1) MFK(2) MFK(3) }

    // phase 5: gates
    short hb[4];
#pragma unroll
    for (int reg = 0; reg < 4; ++reg) {
      float iv = sigmoidf_(acc[0][reg]);
      float fv = sigmoidf_(acc[1][reg]);
      float gv = tanhf_(acc[2][reg]);
      float ov = sigmoidf_(acc[3][reg]);
      float cc = fv * c4[reg] + iv * gv;
      c4[reg] = cc;
      hb[reg] = f2bf(ov * tanhf_(cc));
    }

    // phase 6: DUAL-POST the tagged 16B slab -- plain store INTO the shared
    // L2 (fast-path rendezvous) first, then sc0sc1 store to the mirror
    // (system-visible insurance; fire-and-forget). Then LDS writes.
    {
      const uint32_t tg1 = (uint32_t)(t + 1) << 16;
      uint32_t* ds = xchg + SLABD((t + 1) & 1, cg);
      uint32_t* dsm = ds + MIRROR_OFF;
      u32x4 pv = (u32x4){tg1 | (uint16_t)hb[0], tg1 | (uint16_t)hb[1],
                         tg1 | (uint16_t)hb[2], tg1 | (uint16_t)hb[3]};
      asm volatile("global_store_dwordx4 %0, %1, off" ::"v"(ds), "v"(pv)
                   : "memory");
      asm volatile("global_store_dwordx4 %0, %1, off sc0 sc1" ::"v"(dsm),
                   "v"(pv)
                   : "memory");
    }
    {
      const int ocol = klo * 32 + w * 16 + l15;
#pragma unroll
      for (int reg = 0; reg < 4; ++reg)
        Anx[(quad * 4 + reg) * LDSTRIDE + ocol] = hb[reg];
      Anx[xr * LDSTRIDE + 256 + xd] = f2bf(xv);
    }
    // phase 7: own-half h_{t+1} + x_{t+1} visible (LDS-only; slab store acks
    // must NOT gate the next step)
    BARRIER_LGKM();
  }
#undef MFK

  // ---- final exchange: complete h_256 (parity 0, tag 256) for the FC ----
  // cold path: mirror/system loads only (always correct, placement-agnostic)
  {
    const uint32_t* sam = xchg + SLABD(0, cg ^ 1) + MIRROR_OFF;
    const uint32_t want = 256u << 16;
    u32x4 sv = load16_sys(sam);
    for (;;) {
      const uint32_t bad = ((sv[0] ^ want) | (sv[1] ^ want) | (sv[2] ^ want) |
                            (sv[3] ^ want)) & 0xFFFF0000u;
      if (!bad) break;
      __builtin_amdgcn_s_sleep(2);
      sv = load16_sys(sam);
    }
    const int scol = kro * 32 + w * 16 + l15;
    A[0][(quad * 4 + 0) * LDSTRIDE + scol] = (short)(uint16_t)sv[0];
    A[0][(quad * 4 + 1) * LDSTRIDE + scol] = (short)(uint16_t)sv[1];
    A[0][(quad * 4 + 2) * LDSTRIDE + scol] = (short)(uint16_t)sv[2];
    A[0][(quad * 4 + 3) * LDSTRIDE + scol] = (short)(uint16_t)sv[3];
  }
  __syncthreads();  // cold path: full barrier fine

  // FC epilogue: wave w -> out rows bt*16..+16, cols (cg*8+w)*16..+16
  {
    const int ct = cg * 8 + w;
    const int col = ct * 16 + l15;
    const float bv = b_fc[col];
    f32x4 ao = (f32x4){0.f, 0.f, 0.f, 0.f};
#pragma unroll
    for (int kt = 0; kt < 8; ++kt) {
      const short8 a = *(const short8*)&A[0][l15 * LDSTRIDE + kt * 32 + quad * 8];
      const short8 b = wfc[(size_t)(kt * 16 + ct) * 64 + lane];
      ao = __builtin_amdgcn_mfma_f32_16x16x32_bf16(a, b, ao, 0, 0, 0);
    }
#pragma unroll
    for (int reg = 0; reg < 4; ++reg) {
      const int row = row0 + quad * 4 + reg;
      out[(size_t)row * 256 + col] = ao[reg] + bv;
    }
  }
}

extern "C" void kernel_launch(void* const* d_in, const int* in_sizes, int n_in,
                              void* d_out, int out_size, void* d_ws, size_t ws_size,
                              hipStream_t stream) {
  const float* obs  = (const float*)d_in[0];   // [2048,256,32]
  const float* W_ih = (const float*)d_in[1];   // [1024,32]
  const float* W_hh = (const float*)d_in[2];   // [1024,256]
  const float* b_ih = (const float*)d_in[3];   // [1024]
  const float* b_hh = (const float*)d_in[4];   // [1024]
  const float* W_fc = (const float*)d_in[5];   // [256,256]
  const float* b_fc = (const float*)d_in[6];   // [256]
  float* out = (float*)d_out;                  // [2048,256]

  // ws layout
  short*    wpack = (short*)d_ws;                      // 576*512 shorts = 576 KB
  short*    wfcp  = wpack + 576 * 512;                 // 128*512 shorts = 128 KB
  uint32_t* xchg  = (uint32_t*)((char*)d_ws + (576 + 128) * 1024);  // 8 MB
                                                       // (4MB slab + 4MB mirror)

  hipLaunchKernelGGL(zero_xchg, dim3(1024), dim3(256), 0, stream, (ull*)xchg);
  hipLaunchKernelGGL(pack_w, dim3(144), dim3(256), 0, stream, W_hh, W_ih, wpack);
  hipLaunchKernelGGL(pack_wfc, dim3(32), dim3(256), 0, stream, W_fc, wfcp);
  hipLaunchKernelGGL(lstm_main, dim3(256), dim3(512), 0, stream, obs,
                     (const short8*)wpack, (const short8*)wfcp,
                     b_ih, b_hh, b_fc, xchg, out);
}